// Round 3
// baseline (217.491 us; speedup 1.0000x reference)
//
#include <hip/hip_runtime.h>
#include <math.h>

// SquaredGaussianMixture: N=2M points, D=4, K=8, scalar f32 output.
// prep_kernel (1 wave, f64, writes packed params to ws GLOBAL memory) ->
// point_kernel (2048x256, 4-pt ILP, last-block-fused final reduction).
// Identity: sum_n d^T W d = sum_{ij} W_ij P_ij, P_ij = sum_n d_i d_j:
// hot loop only accumulates 36 symmetric products; W applied once at the end.
//
// R1/R2 lesson: params MUST come from a global __restrict__ pointer so the
// compiler emits rematerializable s_loads (constant cache). Fusing prep into
// point via LDS+readfirstlane pins 120 uniform floats in VGPRs -> guaranteed
// spill (46/42us point). This file reverts the hot loop to the verified R0
// code exactly; the only structural change vs R0 is final_kernel fused into
// point_kernel via ticket counter (saves one dispatch + gap).

struct WsLayout {
  double P[36][32];  // [pair][slot] — slot = blockIdx&31 spreads atomic contention
  double Wp[36];     // softmax weight * (1 or 2 for off-diag), triangular order
  double logz;
  float a2[8][10];   // quadratic coeffs, -0.5*log2e folded, off-diag doubled
  float bb[8][4];    // linear coeffs (log2e * Sinv*mu)
  float cc[8];       // log2(coef_k) - 0.5*log2e*mu^T Sinv mu
  unsigned int ticket;  // last-block-finishes counter (zeroed by prep)
};

__device__ inline void chol4(const double S[4][4], double G[4][4]) {
  #pragma unroll
  for (int i = 0; i < 4; ++i) {
    #pragma unroll
    for (int j = 0; j < 4; ++j) {
      if (j > i) { G[i][j] = 0.0; continue; }
      double s = S[i][j];
      #pragma unroll
      for (int m = 0; m < 4; ++m) if (m < j) s -= G[i][m] * G[j][m];
      if (i == j) G[i][j] = sqrt(s);
      else        G[i][j] = s / G[j][j];
    }
  }
}

__global__ void prep_kernel(const float* __restrict__ means,
                            const float* __restrict__ chols,
                            const float* __restrict__ weights,
                            WsLayout* ws) {
  __shared__ double sig[8][4][4];
  const double LOG2E = 1.4426950408889634074;
  const double LN2PI = 1.8378770664093454836;
  const int t = threadIdx.x;  // 0..63, one wave

  if (t < 8) {
    const int k = t;
    double L[4][4], S[4][4];
    #pragma unroll
    for (int i = 0; i < 4; ++i)
      #pragma unroll
      for (int j = 0; j < 4; ++j)
        L[i][j] = (j <= i) ? (double)chols[k * 16 + i * 4 + j] : 0.0;
    #pragma unroll
    for (int i = 0; i < 4; ++i)
      #pragma unroll
      for (int j = 0; j < 4; ++j) {
        double s = (i == j) ? 1.0 : 0.0;
        #pragma unroll
        for (int m = 0; m < 4; ++m) s += L[i][m] * L[j][m];
        S[i][j] = s;
        sig[k][i][j] = s;
      }
    double G[4][4];
    chol4(S, G);
    const double logdet =
        2.0 * (log(G[0][0]) + log(G[1][1]) + log(G[2][2]) + log(G[3][3]));
    double Gi[4][4];
    #pragma unroll
    for (int j = 0; j < 4; ++j) {
      #pragma unroll
      for (int i = 0; i < 4; ++i) {
        if (i < j) { Gi[i][j] = 0.0; continue; }
        double s = (i == j) ? 1.0 : 0.0;
        #pragma unroll
        for (int m = 0; m < 4; ++m)
          if (m >= j && m < i) s -= G[i][m] * Gi[m][j];
        Gi[i][j] = s / G[i][i];
      }
    }
    double A[4][4];
    #pragma unroll
    for (int i = 0; i < 4; ++i)
      #pragma unroll
      for (int j = 0; j < 4; ++j) {
        double s = 0.0;
        #pragma unroll
        for (int m = 0; m < 4; ++m) s += Gi[m][i] * Gi[m][j];
        A[i][j] = s;
      }
    double mu[4];
    #pragma unroll
    for (int i = 0; i < 4; ++i) mu[i] = (double)means[k * 4 + i];
    double bmu[4];
    #pragma unroll
    for (int i = 0; i < 4; ++i) {
      double s = 0.0;
      #pragma unroll
      for (int j = 0; j < 4; ++j) s += A[i][j] * mu[j];
      bmu[i] = s;
    }
    double muAmu = 0.0;
    #pragma unroll
    for (int i = 0; i < 4; ++i) muAmu += mu[i] * bmu[i];
    const double logcoef = -0.5 * (4.0 * LN2PI + logdet);
    int tt = 0;
    #pragma unroll
    for (int i = 0; i < 4; ++i)
      #pragma unroll
      for (int j = i; j < 4; ++j, ++tt)
        ws->a2[k][tt] =
            (float)(-0.5 * LOG2E * A[i][j] * ((i == j) ? 1.0 : 2.0));
    #pragma unroll
    for (int i = 0; i < 4; ++i) ws->bb[k][i] = (float)(LOG2E * bmu[i]);
    ws->cc[k] = (float)(LOG2E * (logcoef - 0.5 * muAmu));
  }
  __syncthreads();

  // pairwise part: one thread per (i,j) of 8x8
  const int i = t >> 3, j = t & 7;
  const double wij = (double)weights[i] * (double)weights[j];
  double m = wij;
  #pragma unroll
  for (int o = 32; o > 0; o >>= 1) {
    double x = __shfl_xor(m, o, 64);
    m = fmax(m, x);
  }
  const double e = exp(wij - m);
  double ssum = e;
  #pragma unroll
  for (int o = 32; o > 0; o >>= 1) ssum += __shfl_xor(ssum, o, 64);
  const double Wij = e / ssum;

  double SS[4][4];
  #pragma unroll
  for (int a = 0; a < 4; ++a)
    #pragma unroll
    for (int b = 0; b < 4; ++b) SS[a][b] = sig[i][a][b] + sig[j][a][b];
  double G2[4][4];
  chol4(SS, G2);
  const double logdetS =
      2.0 * (log(G2[0][0]) + log(G2[1][1]) + log(G2[2][2]) + log(G2[3][3]));
  double bvec[4], y[4];
  #pragma unroll
  for (int a = 0; a < 4; ++a)
    bvec[a] = (double)means[i * 4 + a] - (double)means[j * 4 + a];
  #pragma unroll
  for (int a = 0; a < 4; ++a) {
    double s = bvec[a];
    #pragma unroll
    for (int mm = 0; mm < 4; ++mm) if (mm < a) s -= G2[a][mm] * y[mm];
    y[a] = s / G2[a][a];
  }
  const double md = y[0]*y[0] + y[1]*y[1] + y[2]*y[2] + y[3]*y[3];
  double zterm = Wij * exp(-0.5 * md - 0.5 * (4.0 * LN2PI + logdetS));
  #pragma unroll
  for (int o = 32; o > 0; o >>= 1) zterm += __shfl_xor(zterm, o, 64);
  if (t == 0) ws->logz = log(zterm);

  // triangular-packed weight (off-diag doubled)
  if (i <= j) {
    const int u = 8 * i - (i * (i - 1)) / 2 + (j - i);
    ws->Wp[u] = Wij * ((i == j) ? 1.0 : 2.0);
  }
  // zero the P accumulator slots + ticket (ws is poisoned 0xAA every call)
  double* Pf = &ws->P[0][0];
  for (int u = t; u < 36 * 32; u += 64) Pf[u] = 0.0;
  if (t == 0) ws->ticket = 0u;
}

__global__ __launch_bounds__(256, 4) void point_kernel(
    const float4* __restrict__ X, const float* __restrict__ par,
    double* __restrict__ accg, WsLayout* ws, float* out, int n) {
  // wave-uniform parameter loads (restrict => s_load into SGPRs,
  // rematerializable from constant cache — do NOT route through LDS)
  float a2[8][10], bb[8][4], cc[8];
  #pragma unroll
  for (int k = 0; k < 8; ++k) {
    #pragma unroll
    for (int u = 0; u < 10; ++u) a2[k][u] = par[k * 10 + u];
    #pragma unroll
    for (int u = 0; u < 4; ++u) bb[k][u] = par[80 + k * 4 + u];
    cc[k] = par[112 + k];
  }
  float acc[36];
  #pragma unroll
  for (int u = 0; u < 36; ++u) acc[u] = 0.0f;

  const int S = gridDim.x * blockDim.x;
  const int idx = blockIdx.x * blockDim.x + threadIdx.x;
  for (int base = idx; base < n; base += 4 * S) {
    // 4 independent strided loads issued before any compute (MLP)
    float4 v[4];
    float kill[4];
    #pragma unroll
    for (int j = 0; j < 4; ++j) {
      const int ij = base + j * S;
      const bool ok = ij < n;
      kill[j] = ok ? 0.0f : -1.0e30f;  // exp2(-1e30) == 0 masks invalid point
      v[j] = X[ok ? ij : 0];
    }
    #pragma unroll
    for (int j = 0; j < 4; ++j) {
      const float4 vv = v[j];
      const float p[10] = {vv.x * vv.x, vv.x * vv.y, vv.x * vv.z, vv.x * vv.w,
                           vv.y * vv.y, vv.y * vv.z, vv.y * vv.w,
                           vv.z * vv.z, vv.z * vv.w, vv.w * vv.w};
      float d[8];
      #pragma unroll
      for (int k = 0; k < 8; ++k) {
        float a = cc[k] + kill[j];
        #pragma unroll
        for (int u = 0; u < 10; ++u) a = fmaf(a2[k][u], p[u], a);
        a = fmaf(bb[k][0], vv.x, a);
        a = fmaf(bb[k][1], vv.y, a);
        a = fmaf(bb[k][2], vv.z, a);
        a = fmaf(bb[k][3], vv.w, a);
        d[k] = __builtin_amdgcn_exp2f(a);
      }
      int u = 0;
      #pragma unroll
      for (int a_ = 0; a_ < 8; ++a_)
        #pragma unroll
        for (int b_ = a_; b_ < 8; ++b_, ++u)
          acc[u] = fmaf(d[a_], d[b_], acc[u]);
    }
  }

  // block reduction: wave butterfly -> LDS -> one f64 atomic per accumulator
  const int lane = threadIdx.x & 63;
  const int wid = threadIdx.x >> 6;
  __shared__ float lred[4][36];
  #pragma unroll
  for (int u = 0; u < 36; ++u) {
    float vv = acc[u];
    #pragma unroll
    for (int o = 32; o > 0; o >>= 1) vv += __shfl_xor(vv, o, 64);
    if (lane == 0) lred[wid][u] = vv;
  }
  __syncthreads();
  if (threadIdx.x < 36) {
    const double s = (double)lred[0][threadIdx.x] + (double)lred[1][threadIdx.x] +
                     (double)lred[2][threadIdx.x] + (double)lred[3][threadIdx.x];
    // spread contention over 32 slots per accumulator
    unsafeAtomicAdd(&accg[threadIdx.x * 32 + (blockIdx.x & 31)], s);
  }

  // ---- last-block-finishes final reduction (replaces final_kernel) ----
  __threadfence();  // release our P atomics before taking a ticket
  __shared__ unsigned int lastflag;
  if (threadIdx.x == 0)
    lastflag = (atomicAdd(&ws->ticket, 1u) == gridDim.x - 1) ? 1u : 0u;
  __syncthreads();
  if (lastflag && threadIdx.x < 64) {
    const int t = threadIdx.x;
    double val = 0.0;
    if (t < 36) {
      double s = 0.0;
      #pragma unroll
      for (int b = 0; b < 32; ++b)
        s += __hip_atomic_load(&ws->P[t][b], __ATOMIC_RELAXED,
                               __HIP_MEMORY_SCOPE_AGENT);
      val = ws->Wp[t] * s;  // Wp/logz written by prep (prior kernel): visible
    }
    #pragma unroll
    for (int o = 32; o > 0; o >>= 1) val += __shfl_xor(val, o, 64);
    if (t == 0) out[0] = (float)(-(log(val) - ws->logz) / (double)n);
  }
}

extern "C" void kernel_launch(void* const* d_in, const int* in_sizes, int n_in,
                              void* d_out, int out_size, void* d_ws, size_t ws_size,
                              hipStream_t stream) {
  const float* X       = (const float*)d_in[0];
  const float* means   = (const float*)d_in[1];
  const float* chols   = (const float*)d_in[2];
  const float* weights = (const float*)d_in[3];
  const int npoints = in_sizes[0] / 4;

  WsLayout* ws = (WsLayout*)d_ws;
  prep_kernel<<<1, 64, 0, stream>>>(means, chols, weights, ws);
  point_kernel<<<2048, 256, 0, stream>>>((const float4*)X, &ws->a2[0][0],
                                         &ws->P[0][0], ws, (float*)d_out,
                                         npoints);
}

// Round 4
// 111.016 us; speedup vs baseline: 1.9591x; 1.9591x over previous
//
#include <hip/hip_runtime.h>
#include <math.h>

// SquaredGaussianMixture: N=2M points, D=4, K=8, scalar f32 output.
// prep_kernel (1 wave, f64) -> point_kernel (2048x256, 4-pt ILP) -> final_kernel.
// Identity: sum_n d^T W d = sum_{ij} W_ij P_ij, P_ij = sum_n d_i d_j:
// hot loop only accumulates 36 symmetric products; W applied once at the end.
//
// Structure notes (measured, R1-R3):
// - prep MUST stay a separate kernel: point's 120 uniform params must come
//   from a global __restrict__ pointer (rematerializable s_loads / constant
//   cache). Routing them through LDS+readfirstlane pins them in VGPRs and
//   spills the hot loop (R1: 46us, R2: 42us vs ~13us here).
// - final MUST stay a separate kernel: fusing it needs __threadfence(),
//   which on gfx950 (non-coherent per-XCD L2) is an L2-writeback per block
//   -> 2048-block flush storm (R3: point 167us at 12.8% VALUBusy).

struct WsLayout {
  double P[36][32];  // [pair][slot] — slot = blockIdx&31 to spread atomic contention
  double Wp[36];     // softmax weight * (1 or 2 for off-diag), triangular order
  double logz;
  float a2[8][10];   // quadratic coeffs, -0.5*log2e folded, off-diag doubled
  float bb[8][4];    // linear coeffs (log2e * Sinv*mu)
  float cc[8];       // log2(coef_k) - 0.5*log2e*mu^T Sinv mu
};

__device__ inline void chol4(const double S[4][4], double G[4][4]) {
  #pragma unroll
  for (int i = 0; i < 4; ++i) {
    #pragma unroll
    for (int j = 0; j < 4; ++j) {
      if (j > i) { G[i][j] = 0.0; continue; }
      double s = S[i][j];
      #pragma unroll
      for (int m = 0; m < 4; ++m) if (m < j) s -= G[i][m] * G[j][m];
      if (i == j) G[i][j] = sqrt(s);
      else        G[i][j] = s / G[j][j];
    }
  }
}

__global__ void prep_kernel(const float* __restrict__ means,
                            const float* __restrict__ chols,
                            const float* __restrict__ weights,
                            WsLayout* ws) {
  __shared__ double sig[8][4][4];
  const double LOG2E = 1.4426950408889634074;
  const double LN2PI = 1.8378770664093454836;
  const int t = threadIdx.x;  // 0..63, one wave

  if (t < 8) {
    const int k = t;
    double L[4][4], S[4][4];
    #pragma unroll
    for (int i = 0; i < 4; ++i)
      #pragma unroll
      for (int j = 0; j < 4; ++j)
        L[i][j] = (j <= i) ? (double)chols[k * 16 + i * 4 + j] : 0.0;
    #pragma unroll
    for (int i = 0; i < 4; ++i)
      #pragma unroll
      for (int j = 0; j < 4; ++j) {
        double s = (i == j) ? 1.0 : 0.0;
        #pragma unroll
        for (int m = 0; m < 4; ++m) s += L[i][m] * L[j][m];
        S[i][j] = s;
        sig[k][i][j] = s;
      }
    double G[4][4];
    chol4(S, G);
    const double logdet =
        2.0 * (log(G[0][0]) + log(G[1][1]) + log(G[2][2]) + log(G[3][3]));
    double Gi[4][4];
    #pragma unroll
    for (int j = 0; j < 4; ++j) {
      #pragma unroll
      for (int i = 0; i < 4; ++i) {
        if (i < j) { Gi[i][j] = 0.0; continue; }
        double s = (i == j) ? 1.0 : 0.0;
        #pragma unroll
        for (int m = 0; m < 4; ++m)
          if (m >= j && m < i) s -= G[i][m] * Gi[m][j];
        Gi[i][j] = s / G[i][i];
      }
    }
    double A[4][4];
    #pragma unroll
    for (int i = 0; i < 4; ++i)
      #pragma unroll
      for (int j = 0; j < 4; ++j) {
        double s = 0.0;
        #pragma unroll
        for (int m = 0; m < 4; ++m) s += Gi[m][i] * Gi[m][j];
        A[i][j] = s;
      }
    double mu[4];
    #pragma unroll
    for (int i = 0; i < 4; ++i) mu[i] = (double)means[k * 4 + i];
    double bmu[4];
    #pragma unroll
    for (int i = 0; i < 4; ++i) {
      double s = 0.0;
      #pragma unroll
      for (int j = 0; j < 4; ++j) s += A[i][j] * mu[j];
      bmu[i] = s;
    }
    double muAmu = 0.0;
    #pragma unroll
    for (int i = 0; i < 4; ++i) muAmu += mu[i] * bmu[i];
    const double logcoef = -0.5 * (4.0 * LN2PI + logdet);
    int tt = 0;
    #pragma unroll
    for (int i = 0; i < 4; ++i)
      #pragma unroll
      for (int j = i; j < 4; ++j, ++tt)
        ws->a2[k][tt] =
            (float)(-0.5 * LOG2E * A[i][j] * ((i == j) ? 1.0 : 2.0));
    #pragma unroll
    for (int i = 0; i < 4; ++i) ws->bb[k][i] = (float)(LOG2E * bmu[i]);
    ws->cc[k] = (float)(LOG2E * (logcoef - 0.5 * muAmu));
  }
  __syncthreads();

  // pairwise part: one thread per (i,j) of 8x8
  const int i = t >> 3, j = t & 7;
  const double wij = (double)weights[i] * (double)weights[j];
  double m = wij;
  #pragma unroll
  for (int o = 32; o > 0; o >>= 1) {
    double x = __shfl_xor(m, o, 64);
    m = fmax(m, x);
  }
  const double e = exp(wij - m);
  double ssum = e;
  #pragma unroll
  for (int o = 32; o > 0; o >>= 1) ssum += __shfl_xor(ssum, o, 64);
  const double Wij = e / ssum;

  double SS[4][4];
  #pragma unroll
  for (int a = 0; a < 4; ++a)
    #pragma unroll
    for (int b = 0; b < 4; ++b) SS[a][b] = sig[i][a][b] + sig[j][a][b];
  double G2[4][4];
  chol4(SS, G2);
  const double logdetS =
      2.0 * (log(G2[0][0]) + log(G2[1][1]) + log(G2[2][2]) + log(G2[3][3]));
  double bvec[4], y[4];
  #pragma unroll
  for (int a = 0; a < 4; ++a)
    bvec[a] = (double)means[i * 4 + a] - (double)means[j * 4 + a];
  #pragma unroll
  for (int a = 0; a < 4; ++a) {
    double s = bvec[a];
    #pragma unroll
    for (int mm = 0; mm < 4; ++mm) if (mm < a) s -= G2[a][mm] * y[mm];
    y[a] = s / G2[a][a];
  }
  const double md = y[0]*y[0] + y[1]*y[1] + y[2]*y[2] + y[3]*y[3];
  double zterm = Wij * exp(-0.5 * md - 0.5 * (4.0 * LN2PI + logdetS));
  #pragma unroll
  for (int o = 32; o > 0; o >>= 1) zterm += __shfl_xor(zterm, o, 64);
  if (t == 0) ws->logz = log(zterm);

  // triangular-packed weight (off-diag doubled)
  if (i <= j) {
    const int u = 8 * i - (i * (i - 1)) / 2 + (j - i);
    ws->Wp[u] = Wij * ((i == j) ? 1.0 : 2.0);
  }
  // zero the P accumulator slots (ws is poisoned 0xAA before every call)
  double* Pf = &ws->P[0][0];
  for (int u = t; u < 36 * 32; u += 64) Pf[u] = 0.0;
}

__global__ __launch_bounds__(256, 4) void point_kernel(
    const float4* __restrict__ X, const float* __restrict__ par,
    double* __restrict__ accg, int n) {
  // wave-uniform parameter loads (restrict => s_load into SGPRs)
  float a2[8][10], bb[8][4], cc[8];
  #pragma unroll
  for (int k = 0; k < 8; ++k) {
    #pragma unroll
    for (int u = 0; u < 10; ++u) a2[k][u] = par[k * 10 + u];
    #pragma unroll
    for (int u = 0; u < 4; ++u) bb[k][u] = par[80 + k * 4 + u];
    cc[k] = par[112 + k];
  }
  float acc[36];
  #pragma unroll
  for (int u = 0; u < 36; ++u) acc[u] = 0.0f;

  const int S = gridDim.x * blockDim.x;
  const int idx = blockIdx.x * blockDim.x + threadIdx.x;
  for (int base = idx; base < n; base += 4 * S) {
    // 4 independent strided loads issued before any compute (MLP)
    float4 v[4];
    float kill[4];
    #pragma unroll
    for (int j = 0; j < 4; ++j) {
      const int ij = base + j * S;
      const bool ok = ij < n;
      kill[j] = ok ? 0.0f : -1.0e30f;  // exp2(-1e30) == 0 masks invalid point
      v[j] = X[ok ? ij : 0];
    }
    #pragma unroll
    for (int j = 0; j < 4; ++j) {
      const float4 vv = v[j];
      const float p[10] = {vv.x * vv.x, vv.x * vv.y, vv.x * vv.z, vv.x * vv.w,
                           vv.y * vv.y, vv.y * vv.z, vv.y * vv.w,
                           vv.z * vv.z, vv.z * vv.w, vv.w * vv.w};
      float d[8];
      #pragma unroll
      for (int k = 0; k < 8; ++k) {
        float a = cc[k] + kill[j];
        #pragma unroll
        for (int u = 0; u < 10; ++u) a = fmaf(a2[k][u], p[u], a);
        a = fmaf(bb[k][0], vv.x, a);
        a = fmaf(bb[k][1], vv.y, a);
        a = fmaf(bb[k][2], vv.z, a);
        a = fmaf(bb[k][3], vv.w, a);
        d[k] = __builtin_amdgcn_exp2f(a);
      }
      int u = 0;
      #pragma unroll
      for (int a_ = 0; a_ < 8; ++a_)
        #pragma unroll
        for (int b_ = a_; b_ < 8; ++b_, ++u)
          acc[u] = fmaf(d[a_], d[b_], acc[u]);
    }
  }

  // block reduction: wave butterfly -> LDS -> one f64 atomic per accumulator
  const int lane = threadIdx.x & 63;
  const int wid = threadIdx.x >> 6;
  __shared__ float lred[4][36];
  #pragma unroll
  for (int u = 0; u < 36; ++u) {
    float vv = acc[u];
    #pragma unroll
    for (int o = 32; o > 0; o >>= 1) vv += __shfl_xor(vv, o, 64);
    if (lane == 0) lred[wid][u] = vv;
  }
  __syncthreads();
  if (threadIdx.x < 36) {
    const double s = (double)lred[0][threadIdx.x] + (double)lred[1][threadIdx.x] +
                     (double)lred[2][threadIdx.x] + (double)lred[3][threadIdx.x];
    // spread contention over 32 slots per accumulator
    unsafeAtomicAdd(&accg[threadIdx.x * 32 + (blockIdx.x & 31)], s);
  }
}

__global__ void final_kernel(const WsLayout* __restrict__ ws,
                             float* __restrict__ out, int n) {
  const int t = threadIdx.x;
  double val = 0.0;
  if (t < 36) {
    double s = 0.0;
    #pragma unroll
    for (int b = 0; b < 32; ++b) s += ws->P[t][b];
    val = ws->Wp[t] * s;
  }
  #pragma unroll
  for (int o = 32; o > 0; o >>= 1) val += __shfl_xor(val, o, 64);
  if (t == 0) out[0] = (float)(-(log(val) - ws->logz) / (double)n);
}

extern "C" void kernel_launch(void* const* d_in, const int* in_sizes, int n_in,
                              void* d_out, int out_size, void* d_ws, size_t ws_size,
                              hipStream_t stream) {
  const float* X       = (const float*)d_in[0];
  const float* means   = (const float*)d_in[1];
  const float* chols   = (const float*)d_in[2];
  const float* weights = (const float*)d_in[3];
  const int npoints = in_sizes[0] / 4;

  WsLayout* ws = (WsLayout*)d_ws;
  prep_kernel<<<1, 64, 0, stream>>>(means, chols, weights, ws);
  point_kernel<<<2048, 256, 0, stream>>>((const float4*)X, &ws->a2[0][0],
                                         &ws->P[0][0], npoints);
  final_kernel<<<1, 64, 0, stream>>>(ws, (float*)d_out, npoints);
}

// Round 5
// 105.910 us; speedup vs baseline: 2.0535x; 1.0482x over previous
//
#include <hip/hip_runtime.h>
#include <math.h>

// SquaredGaussianMixture: N=2M points, D=4, K=8, scalar f32 output.
// prep_kernel (1 wave, f64) -> point_kernel (1024x256, 8-pt ILP) -> final_kernel.
// Identity: sum_n d^T W d = sum_{ij} W_ij P_ij, P_ij = sum_n d_i d_j:
// hot loop only accumulates 36 symmetric products; W applied once at the end.
//
// Structure notes (measured, R1-R4):
// - prep MUST stay a separate kernel: point's 120 uniform params must come
//   from a global __restrict__ pointer (rematerializable s_loads / constant
//   cache). Routing them through LDS+readfirstlane pins them in VGPRs and
//   spills the hot loop (R1: 46us, R2: 42us vs ~13us here).
// - final MUST stay a separate kernel: fusing it needs __threadfence(),
//   which on gfx950 (non-coherent per-XCD L2) is an L2-writeback per block
//   -> 2048-block flush storm (R3: point 167us at 12.8% VALUBusy).
// - R5 change: 2048 blocks/4-pt -> 1024 blocks/8-pt. Per-thread reduction
//   tail (36 accs x 6 butterfly stages = 216 shuffles) is paid per THREAD,
//   and 2048 blocks = 2 sequential dispatch rounds at 4 blocks/CU. Halving
//   threads halves total tail + param-load work and gives exactly 1 round.

struct WsLayout {
  double P[36][32];  // [pair][slot] — slot = blockIdx&31 to spread atomic contention
  double Wp[36];     // softmax weight * (1 or 2 for off-diag), triangular order
  double logz;
  float a2[8][10];   // quadratic coeffs, -0.5*log2e folded, off-diag doubled
  float bb[8][4];    // linear coeffs (log2e * Sinv*mu)
  float cc[8];       // log2(coef_k) - 0.5*log2e*mu^T Sinv mu
};

__device__ inline void chol4(const double S[4][4], double G[4][4]) {
  #pragma unroll
  for (int i = 0; i < 4; ++i) {
    #pragma unroll
    for (int j = 0; j < 4; ++j) {
      if (j > i) { G[i][j] = 0.0; continue; }
      double s = S[i][j];
      #pragma unroll
      for (int m = 0; m < 4; ++m) if (m < j) s -= G[i][m] * G[j][m];
      if (i == j) G[i][j] = sqrt(s);
      else        G[i][j] = s / G[j][j];
    }
  }
}

__global__ void prep_kernel(const float* __restrict__ means,
                            const float* __restrict__ chols,
                            const float* __restrict__ weights,
                            WsLayout* ws) {
  __shared__ double sig[8][4][4];
  const double LOG2E = 1.4426950408889634074;
  const double LN2PI = 1.8378770664093454836;
  const int t = threadIdx.x;  // 0..63, one wave

  if (t < 8) {
    const int k = t;
    double L[4][4], S[4][4];
    #pragma unroll
    for (int i = 0; i < 4; ++i)
      #pragma unroll
      for (int j = 0; j < 4; ++j)
        L[i][j] = (j <= i) ? (double)chols[k * 16 + i * 4 + j] : 0.0;
    #pragma unroll
    for (int i = 0; i < 4; ++i)
      #pragma unroll
      for (int j = 0; j < 4; ++j) {
        double s = (i == j) ? 1.0 : 0.0;
        #pragma unroll
        for (int m = 0; m < 4; ++m) s += L[i][m] * L[j][m];
        S[i][j] = s;
        sig[k][i][j] = s;
      }
    double G[4][4];
    chol4(S, G);
    const double logdet =
        2.0 * (log(G[0][0]) + log(G[1][1]) + log(G[2][2]) + log(G[3][3]));
    double Gi[4][4];
    #pragma unroll
    for (int j = 0; j < 4; ++j) {
      #pragma unroll
      for (int i = 0; i < 4; ++i) {
        if (i < j) { Gi[i][j] = 0.0; continue; }
        double s = (i == j) ? 1.0 : 0.0;
        #pragma unroll
        for (int m = 0; m < 4; ++m)
          if (m >= j && m < i) s -= G[i][m] * Gi[m][j];
        Gi[i][j] = s / G[i][i];
      }
    }
    double A[4][4];
    #pragma unroll
    for (int i = 0; i < 4; ++i)
      #pragma unroll
      for (int j = 0; j < 4; ++j) {
        double s = 0.0;
        #pragma unroll
        for (int m = 0; m < 4; ++m) s += Gi[m][i] * Gi[m][j];
        A[i][j] = s;
      }
    double mu[4];
    #pragma unroll
    for (int i = 0; i < 4; ++i) mu[i] = (double)means[k * 4 + i];
    double bmu[4];
    #pragma unroll
    for (int i = 0; i < 4; ++i) {
      double s = 0.0;
      #pragma unroll
      for (int j = 0; j < 4; ++j) s += A[i][j] * mu[j];
      bmu[i] = s;
    }
    double muAmu = 0.0;
    #pragma unroll
    for (int i = 0; i < 4; ++i) muAmu += mu[i] * bmu[i];
    const double logcoef = -0.5 * (4.0 * LN2PI + logdet);
    int tt = 0;
    #pragma unroll
    for (int i = 0; i < 4; ++i)
      #pragma unroll
      for (int j = i; j < 4; ++j, ++tt)
        ws->a2[k][tt] =
            (float)(-0.5 * LOG2E * A[i][j] * ((i == j) ? 1.0 : 2.0));
    #pragma unroll
    for (int i = 0; i < 4; ++i) ws->bb[k][i] = (float)(LOG2E * bmu[i]);
    ws->cc[k] = (float)(LOG2E * (logcoef - 0.5 * muAmu));
  }
  __syncthreads();

  // pairwise part: one thread per (i,j) of 8x8
  const int i = t >> 3, j = t & 7;
  const double wij = (double)weights[i] * (double)weights[j];
  double m = wij;
  #pragma unroll
  for (int o = 32; o > 0; o >>= 1) {
    double x = __shfl_xor(m, o, 64);
    m = fmax(m, x);
  }
  const double e = exp(wij - m);
  double ssum = e;
  #pragma unroll
  for (int o = 32; o > 0; o >>= 1) ssum += __shfl_xor(ssum, o, 64);
  const double Wij = e / ssum;

  double SS[4][4];
  #pragma unroll
  for (int a = 0; a < 4; ++a)
    #pragma unroll
    for (int b = 0; b < 4; ++b) SS[a][b] = sig[i][a][b] + sig[j][a][b];
  double G2[4][4];
  chol4(SS, G2);
  const double logdetS =
      2.0 * (log(G2[0][0]) + log(G2[1][1]) + log(G2[2][2]) + log(G2[3][3]));
  double bvec[4], y[4];
  #pragma unroll
  for (int a = 0; a < 4; ++a)
    bvec[a] = (double)means[i * 4 + a] - (double)means[j * 4 + a];
  #pragma unroll
  for (int a = 0; a < 4; ++a) {
    double s = bvec[a];
    #pragma unroll
    for (int mm = 0; mm < 4; ++mm) if (mm < a) s -= G2[a][mm] * y[mm];
    y[a] = s / G2[a][a];
  }
  const double md = y[0]*y[0] + y[1]*y[1] + y[2]*y[2] + y[3]*y[3];
  double zterm = Wij * exp(-0.5 * md - 0.5 * (4.0 * LN2PI + logdetS));
  #pragma unroll
  for (int o = 32; o > 0; o >>= 1) zterm += __shfl_xor(zterm, o, 64);
  if (t == 0) ws->logz = log(zterm);

  // triangular-packed weight (off-diag doubled)
  if (i <= j) {
    const int u = 8 * i - (i * (i - 1)) / 2 + (j - i);
    ws->Wp[u] = Wij * ((i == j) ? 1.0 : 2.0);
  }
  // zero the P accumulator slots (ws is poisoned 0xAA before every call)
  double* Pf = &ws->P[0][0];
  for (int u = t; u < 36 * 32; u += 64) Pf[u] = 0.0;
}

__global__ __launch_bounds__(256, 4) void point_kernel(
    const float4* __restrict__ X, const float* __restrict__ par,
    double* __restrict__ accg, int n) {
  // wave-uniform parameter loads (restrict => s_load into SGPRs)
  float a2[8][10], bb[8][4], cc[8];
  #pragma unroll
  for (int k = 0; k < 8; ++k) {
    #pragma unroll
    for (int u = 0; u < 10; ++u) a2[k][u] = par[k * 10 + u];
    #pragma unroll
    for (int u = 0; u < 4; ++u) bb[k][u] = par[80 + k * 4 + u];
    cc[k] = par[112 + k];
  }
  float acc[36];
  #pragma unroll
  for (int u = 0; u < 36; ++u) acc[u] = 0.0f;

  const int S = gridDim.x * blockDim.x;
  const int idx = blockIdx.x * blockDim.x + threadIdx.x;
  for (int base = idx; base < n; base += 8 * S) {
    // 8 independent strided loads issued before any compute (MLP)
    float4 v[8];
    float kill[8];
    #pragma unroll
    for (int j = 0; j < 8; ++j) {
      const int ij = base + j * S;
      const bool ok = ij < n;
      kill[j] = ok ? 0.0f : -1.0e30f;  // exp2(-1e30) == 0 masks invalid point
      v[j] = X[ok ? ij : 0];
    }
    #pragma unroll
    for (int j = 0; j < 8; ++j) {
      const float4 vv = v[j];
      const float p[10] = {vv.x * vv.x, vv.x * vv.y, vv.x * vv.z, vv.x * vv.w,
                           vv.y * vv.y, vv.y * vv.z, vv.y * vv.w,
                           vv.z * vv.z, vv.z * vv.w, vv.w * vv.w};
      float d[8];
      #pragma unroll
      for (int k = 0; k < 8; ++k) {
        float a = cc[k] + kill[j];
        #pragma unroll
        for (int u = 0; u < 10; ++u) a = fmaf(a2[k][u], p[u], a);
        a = fmaf(bb[k][0], vv.x, a);
        a = fmaf(bb[k][1], vv.y, a);
        a = fmaf(bb[k][2], vv.z, a);
        a = fmaf(bb[k][3], vv.w, a);
        d[k] = __builtin_amdgcn_exp2f(a);
      }
      int u = 0;
      #pragma unroll
      for (int a_ = 0; a_ < 8; ++a_)
        #pragma unroll
        for (int b_ = a_; b_ < 8; ++b_, ++u)
          acc[u] = fmaf(d[a_], d[b_], acc[u]);
    }
  }

  // block reduction: wave butterfly -> LDS -> one f64 atomic per accumulator
  const int lane = threadIdx.x & 63;
  const int wid = threadIdx.x >> 6;
  __shared__ float lred[4][36];
  #pragma unroll
  for (int u = 0; u < 36; ++u) {
    float vv = acc[u];
    #pragma unroll
    for (int o = 32; o > 0; o >>= 1) vv += __shfl_xor(vv, o, 64);
    if (lane == 0) lred[wid][u] = vv;
  }
  __syncthreads();
  if (threadIdx.x < 36) {
    const double s = (double)lred[0][threadIdx.x] + (double)lred[1][threadIdx.x] +
                     (double)lred[2][threadIdx.x] + (double)lred[3][threadIdx.x];
    // spread contention over 32 slots per accumulator
    unsafeAtomicAdd(&accg[threadIdx.x * 32 + (blockIdx.x & 31)], s);
  }
}

__global__ void final_kernel(const WsLayout* __restrict__ ws,
                             float* __restrict__ out, int n) {
  const int t = threadIdx.x;
  double val = 0.0;
  if (t < 36) {
    double s = 0.0;
    #pragma unroll
    for (int b = 0; b < 32; ++b) s += ws->P[t][b];
    val = ws->Wp[t] * s;
  }
  #pragma unroll
  for (int o = 32; o > 0; o >>= 1) val += __shfl_xor(val, o, 64);
  if (t == 0) out[0] = (float)(-(log(val) - ws->logz) / (double)n);
}

extern "C" void kernel_launch(void* const* d_in, const int* in_sizes, int n_in,
                              void* d_out, int out_size, void* d_ws, size_t ws_size,
                              hipStream_t stream) {
  const float* X       = (const float*)d_in[0];
  const float* means   = (const float*)d_in[1];
  const float* chols   = (const float*)d_in[2];
  const float* weights = (const float*)d_in[3];
  const int npoints = in_sizes[0] / 4;

  WsLayout* ws = (WsLayout*)d_ws;
  prep_kernel<<<1, 64, 0, stream>>>(means, chols, weights, ws);
  point_kernel<<<1024, 256, 0, stream>>>((const float4*)X, &ws->a2[0][0],
                                         &ws->P[0][0], npoints);
  final_kernel<<<1, 64, 0, stream>>>(ws, (float*)d_out, npoints);
}